// Round 14
// baseline (580.302 us; speedup 1.0000x reference)
//
#include <hip/hip_runtime.h>

static constexpr int N_ = 40000;
static constexpr int E_ = 1280000;
static constexpr int EH = E_ / 2;       // 640,000 slots per pass
static constexpr int NS = N_ * 64;      // 2,560,000 scalar elems
static constexpr int NV = N_ * 48;      // 1,920,000 vector elems

typedef _Float16 half2_t __attribute__((ext_vector_type(2)));
typedef _Float16 half8_t __attribute__((ext_vector_type(8)));
typedef float float4_t __attribute__((ext_vector_type(4)));
typedef unsigned int uint;

__device__ __forceinline__ float silu_f(float x) { return __fdividef(x, 1.f + __expf(-x)); }
__device__ __forceinline__ int rfl(int x) { return __builtin_amdgcn_readfirstlane(x); }

// ---- per-node attention precompute ----
__global__ void k_precompute(const float* __restrict__ scalars, const float* __restrict__ Wa1,
                             const float* __restrict__ ba1,
                             float* __restrict__ P1, float* __restrict__ P2)
{
    int t = blockIdx.x * 256 + threadIdx.x;  // t < N*64
    int n = t >> 6, j = t & 63;
    float a1 = ba1[j];
    float a2 = 0.f;
    const float* srow = scalars + (size_t)n * 64;
#pragma unroll 8
    for (int k = 0; k < 64; k++) {
        float s = srow[k];
        a1 = fmaf(s, Wa1[k * 64 + j], a1);
        a2 = fmaf(s, Wa1[(64 + k) * 64 + j], a2);
    }
    P1[t] = a1;
    P2[t] = a2;
}

// ---- pack MFMA B-operand tables as k-pair half2, col-major ----
// tbl : GW = [Wa1_att(32x64) | W1(32x32)] ;  tbl2 : W2(32x96)
__global__ void k_pack(const float* __restrict__ W1, const float* __restrict__ Wa1,
                       const float* __restrict__ W2, uint* __restrict__ tbl,
                       uint* __restrict__ tbl2)
{
    int t = blockIdx.x * 256 + threadIdx.x;
    if (t < 1536) {
        int j = t >> 4, q = t & 15;
        int k0 = 2 * q, k1 = 2 * q + 1;
        float a = (j < 64) ? Wa1[(128 + k0) * 64 + j] : W1[k0 * 32 + (j - 64)];
        float b = (j < 64) ? Wa1[(128 + k1) * 64 + j] : W1[k1 * 32 + (j - 64)];
        half2_t v; v.x = (_Float16)a; v.y = (_Float16)b;
        tbl[t] = __builtin_bit_cast(uint, v);
    } else if (t < 3072) {
        int tt = t - 1536;
        int j = tt >> 4, q = tt & 15;
        half2_t v;
        v.x = (_Float16)W2[(2 * q + 0) * 96 + j];
        v.y = (_Float16)W2[(2 * q + 1) * 96 + j];
        tbl2[tt] = __builtin_bit_cast(uint, v);
    }
}

// ================= CSR build (round-9 proven) =================
__global__ void k_rank(const int* __restrict__ eidx, int* __restrict__ cnt,
                       int* __restrict__ r)
{
    int e = blockIdx.x * 256 + threadIdx.x;
    r[e] = atomicAdd(&cnt[eidx[E_ + e]], 1);
}

__global__ void k_scan1(const int* __restrict__ cnt, int* __restrict__ row_start,
                        int* __restrict__ bsum)
{
    __shared__ int buf[1024];
    int b = blockIdx.x, tid = threadIdx.x;
    int idx = b * 1024 + tid;
    int v = (idx < N_) ? cnt[idx] : 0;
    buf[tid] = v;
    __syncthreads();
    for (int off = 1; off < 1024; off <<= 1) {
        int t = (tid >= off) ? buf[tid - off] : 0;
        __syncthreads();
        buf[tid] += t;
        __syncthreads();
    }
    if (idx < N_) row_start[idx] = buf[tid] - v;
    if (tid == 1023) bsum[b] = buf[1023];
}

__global__ void k_scan2(const int* __restrict__ bsum, int* __restrict__ boff)
{
    if (threadIdx.x == 0) {
        int s = 0;
        for (int b = 0; b < 40; b++) { boff[b] = s; s += bsum[b]; }
    }
}

__global__ void k_scan3(const int* __restrict__ boff, int* __restrict__ row_start)
{
    int idx = blockIdx.x * 1024 + threadIdx.x;
    if (idx < N_) row_start[idx] += boff[blockIdx.x];
    if (idx == N_) row_start[N_] = E_;
}

__global__ void k_place(const int* __restrict__ eidx, const int* __restrict__ row_start,
                        const int* __restrict__ r, int* __restrict__ perm)
{
    int e = blockIdx.x * 256 + threadIdx.x;
    int dst = eidx[E_ + e];
    perm[row_start[dst] + r[e]] = e;
}

// ================= edge phase: g-MFMA + second MFMA stage F = h @ W2 (per-pass half) ========
// LDS per wave: 64 rows x 208 B (stride 104 halves). Covers slots [slot_base, slot_base+EH).
__global__ __launch_bounds__(256, 3) void k_edges_F(
    const float* __restrict__ edge_vec, const int* __restrict__ eidx,
    const int* __restrict__ perm,
    const float* __restrict__ P1, const float* __restrict__ P2,
    const uint* __restrict__ tbl, const uint* __restrict__ tbl2,
    const float* __restrict__ b1,
    const float* __restrict__ Wa2, const float* __restrict__ ba2,
    float4* __restrict__ attsh, int* __restrict__ srcbuf, _Float16* __restrict__ Fg,
    int slot_base)
{
    __shared__ char lds_raw[4 * 13312];          // 53248 B: 4 waves x (64 x 208 B)
    int tid = threadIdx.x;
    int wid = tid >> 6, lane = tid & 63;
    char* wbase = lds_raw + wid * 13312;
    int bl = lane & 15, bq = lane >> 4;

    int i = slot_base + blockIdx.x * 256 + tid;   // absolute slot
    int e = perm[i];
    int src = eidx[e];
    int dst = eidx[E_ + e];

    float ev0 = edge_vec[3 * e + 0];
    float ev1 = edge_vec[3 * e + 1];
    float ev2 = edge_vec[3 * e + 2];
    float d = sqrtf(fmaf(ev0, ev0, fmaf(ev1, ev1, ev2 * ev2)));
    float inv_d = __fdividef(1.f, fmaxf(d, 1e-8f));
    float cut = (d < 10.f) ? 0.5f * (__cosf(0.31415927f * d) + 1.f) : 0.f;
    float cutd = cut * inv_d;
    float sh0 = ev1 * inv_d, sh1 = ev2 * inv_d, sh2 = ev0 * inv_d;  // [uy, uz, ux]

    // rbf basis packed to half2, staged to LDS rows (64 B/edge)
    uint rbf2[16];
#pragma unroll
    for (int q = 0; q < 16; q++) {
        float r0 = __sinf((float)(2 * q + 1) * 0.31415927f * d) * cutd;
        float r1 = __sinf((float)(2 * q + 2) * 0.31415927f * d) * cutd;
        half2_t v; v.x = (_Float16)r0; v.y = (_Float16)r1;
        rbf2[q] = __builtin_bit_cast(uint, v);
    }
    {
        uint4* rw = (uint4*)(wbase + lane * 64);
        rw[0] = make_uint4(rbf2[0], rbf2[1], rbf2[2], rbf2[3]);
        rw[1] = make_uint4(rbf2[4], rbf2[5], rbf2[6], rbf2[7]);
        rw[2] = make_uint4(rbf2[8], rbf2[9], rbf2[10], rbf2[11]);
        rw[3] = make_uint4(rbf2[12], rbf2[13], rbf2[14], rbf2[15]);
    }

    uint4 bfr[6];
#pragma unroll
    for (int u = 0; u < 6; u++)
        bfr[u] = *(const uint4*)(tbl + (u * 16 + bl) * 16 + bq * 4);

    __syncthreads();   // rbf staged

    uint4 afr[4];
#pragma unroll
    for (int t = 0; t < 4; t++)
        afr[t] = *(const uint4*)(wbase + (t * 16 + bl) * 64 + bq * 16);

    __syncthreads();   // A-frags in VGPRs; tile region free

    _Float16* gtile = (_Float16*)wbase;          // [edge_loc][col], stride 104 halves
#pragma unroll
    for (int t = 0; t < 4; t++) {
        half8_t av = __builtin_bit_cast(half8_t, afr[t]);
        int eb = t * 16 + bq * 4;
#pragma unroll
        for (int u = 0; u < 6; u++) {
            float4_t dd = __builtin_amdgcn_mfma_f32_16x16x32_f16(
                av, __builtin_bit_cast(half8_t, bfr[u]), (float4_t)(0.f), 0, 0, 0);
            int col = u * 16 + bl;
            gtile[(eb + 0) * 104 + col] = (_Float16)dd[0];
            gtile[(eb + 1) * 104 + col] = (_Float16)dd[1];
            gtile[(eb + 2) * 104 + col] = (_Float16)dd[2];
            gtile[(eb + 3) * 104 + col] = (_Float16)dd[3];
        }
    }

    __syncthreads();   // g-tile complete

    const uint* grow = (const uint*)(wbase + (size_t)lane * 208);

    const float4* p14 = (const float4*)(P1 + (size_t)dst * 64);
    const float4* p24 = (const float4*)(P2 + (size_t)src * 64);
    float logit = ba2[0];
#pragma unroll
    for (int q = 0; q < 16; q++) {
        float4 a = p14[q];
        float4 b = p24[q];
        half2_t g01 = __builtin_bit_cast(half2_t, grow[2 * q + 0]);
        half2_t g23 = __builtin_bit_cast(half2_t, grow[2 * q + 1]);
        logit = fmaf(silu_f(a.x + b.x + (float)g01.x), Wa2[4 * q + 0], logit);
        logit = fmaf(silu_f(a.y + b.y + (float)g01.y), Wa2[4 * q + 1], logit);
        logit = fmaf(silu_f(a.z + b.z + (float)g23.x), Wa2[4 * q + 2], logit);
        logit = fmaf(silu_f(a.w + b.w + (float)g23.y), Wa2[4 * q + 3], logit);
    }
    float att = __fdividef(1.f, 1.f + __expf(-logit));

    // h = silu(g[64:96] + b1) packed f16
    uint hp[16];
#pragma unroll
    for (int q = 0; q < 16; q++) {
        half2_t gg = __builtin_bit_cast(half2_t, grow[32 + q]);
        half2_t v;
        v.x = (_Float16)silu_f((float)gg.x + b1[2 * q + 0]);
        v.y = (_Float16)silu_f((float)gg.y + b1[2 * q + 1]);
        hp[q] = __builtin_bit_cast(uint, v);
    }

    uint4 bfr2[6];
#pragma unroll
    for (int u = 0; u < 6; u++)
        bfr2[u] = *(const uint4*)(tbl2 + (u * 16 + bl) * 16 + bq * 4);

    __syncthreads();   // everyone done reading g-tile

    {
        uint4* rw = (uint4*)(wbase + lane * 64);   // stage h rows (64 B/edge)
        rw[0] = make_uint4(hp[0], hp[1], hp[2], hp[3]);
        rw[1] = make_uint4(hp[4], hp[5], hp[6], hp[7]);
        rw[2] = make_uint4(hp[8], hp[9], hp[10], hp[11]);
        rw[3] = make_uint4(hp[12], hp[13], hp[14], hp[15]);
    }

    __syncthreads();   // h staged

    uint4 afr2[4];
#pragma unroll
    for (int t = 0; t < 4; t++)
        afr2[t] = *(const uint4*)(wbase + (t * 16 + bl) * 64 + bq * 16);

    __syncthreads();   // A-frags in VGPRs; tile region free for F

    _Float16* ftile = (_Float16*)wbase;          // [edge_loc][col 0..95], stride 104
#pragma unroll
    for (int t = 0; t < 4; t++) {
        half8_t av = __builtin_bit_cast(half8_t, afr2[t]);
        int eb = t * 16 + bq * 4;
#pragma unroll
        for (int u = 0; u < 6; u++) {
            float4_t dd = __builtin_amdgcn_mfma_f32_16x16x32_f16(
                av, __builtin_bit_cast(half8_t, bfr2[u]), (float4_t)(0.f), 0, 0, 0);
            int col = u * 16 + bl;
            ftile[(eb + 0) * 104 + col] = (_Float16)dd[0];
            ftile[(eb + 1) * 104 + col] = (_Float16)dd[1];
            ftile[(eb + 2) * 104 + col] = (_Float16)dd[2];
            ftile[(eb + 3) * 104 + col] = (_Float16)dd[3];
        }
    }

    __syncthreads();   // F tile complete

    // coalesced row write into the per-pass half buffer
    {
        const uint4* fr = (const uint4*)(wbase + (size_t)lane * 208);
        uint4* fo = (uint4*)(Fg + (size_t)(i - slot_base) * 96);
#pragma unroll
        for (int q = 0; q < 12; q++) fo[q] = fr[q];
    }

    attsh[i] = make_float4(att, sh0, sh1, sh2);
    srcbuf[i] = src;
}

// ================= gather: pure segment-sum over F half, clipped ranges, two passes ==========
// PASS 0: write partial sums to acc. PASS 1: out = residual + acc + partial.
template <int PASS>
__global__ __launch_bounds__(256, 4) void k_gather_F(
    const float* __restrict__ scalars, const float* __restrict__ vectors,
    const float* __restrict__ b2,
    const int* __restrict__ row_start,
    const float4* __restrict__ attsh, const int* __restrict__ srcbuf,
    const _Float16* __restrict__ Fg, int slot_lo, int slot_hi,
    float* __restrict__ acc_ws,
    float* __restrict__ out)
{
    int wid  = threadIdx.x >> 6;
    int lane = threadIdx.x & 63;
    int n    = blockIdx.x * 2 + (wid >> 1);
    int role = wid & 1;
    int rs = rfl(row_start[n]);
    int re = rfl(row_start[n + 1]);
    int a = (rs > slot_lo) ? rs : slot_lo;
    int b = (re < slot_hi) ? re : slot_hi;

    if (role == 0) {
        float bj = b2[lane];
        float acc = 0.f;
        int i = a;
        for (; i + 2 <= b; i += 2) {
            float4 as0 = attsh[i + 0];
            float4 as1 = attsh[i + 1];
            int s0 = srcbuf[i + 0];
            int s1 = srcbuf[i + 1];
            float f0 = (float)Fg[(size_t)(i + 0 - slot_lo) * 96 + lane] + bj;
            float f1 = (float)Fg[(size_t)(i + 1 - slot_lo) * 96 + lane] + bj;
            float g0 = scalars[(size_t)s0 * 64 + lane];
            float g1 = scalars[(size_t)s1 * 64 + lane];
            acc = fmaf(as0.x * g0, f0, acc);
            acc = fmaf(as1.x * g1, f1, acc);
        }
        if (i < b) {
            float4 as = attsh[i];
            int s0 = srcbuf[i];
            float f = (float)Fg[(size_t)(i - slot_lo) * 96 + lane] + bj;
            acc = fmaf(as.x * scalars[(size_t)s0 * 64 + lane], f, acc);
        }
        size_t o = (size_t)n * 64 + lane;
        if (PASS == 0) acc_ws[o] = acc;
        else           out[o] = scalars[o] + acc_ws[o] + acc;
    } else if (lane < 48) {
        int m = lane / 3;
        int c = lane - 3 * m;
        float bf = b2[64 + m], bg = b2[80 + m];
        float acc = 0.f;
        int i = a;
        for (; i + 2 <= b; i += 2) {
            float4 as0 = attsh[i + 0];
            float4 as1 = attsh[i + 1];
            int s0 = srcbuf[i + 0];
            int s1 = srcbuf[i + 1];
            float vf0 = (float)Fg[(size_t)(i + 0 - slot_lo) * 96 + 64 + m] + bf;
            float vg0 = (float)Fg[(size_t)(i + 0 - slot_lo) * 96 + 80 + m] + bg;
            float vf1 = (float)Fg[(size_t)(i + 1 - slot_lo) * 96 + 64 + m] + bf;
            float vg1 = (float)Fg[(size_t)(i + 1 - slot_lo) * 96 + 80 + m] + bg;
            float vj0 = vectors[(size_t)s0 * 48 + lane];
            float vj1 = vectors[(size_t)s1 * 48 + lane];
            float sh0c = (c == 0) ? as0.y : ((c == 1) ? as0.z : as0.w);
            float sh1c = (c == 0) ? as1.y : ((c == 1) ? as1.z : as1.w);
            acc = fmaf(as0.x, fmaf(vj0, vf0, vg0 * sh0c), acc);
            acc = fmaf(as1.x, fmaf(vj1, vf1, vg1 * sh1c), acc);
        }
        if (i < b) {
            float4 as = attsh[i];
            int s0 = srcbuf[i];
            float vf = (float)Fg[(size_t)(i - slot_lo) * 96 + 64 + m] + bf;
            float vg = (float)Fg[(size_t)(i - slot_lo) * 96 + 80 + m] + bg;
            float vjc = vectors[(size_t)s0 * 48 + lane];
            float shc = (c == 0) ? as.y : ((c == 1) ? as.z : as.w);
            acc = fmaf(as.x, fmaf(vjc, vf, vg * shc), acc);
        }
        size_t o = (size_t)n * 48 + lane;
        if (PASS == 0) acc_ws[NS + o] = acc;
        else           out[NS + o] = vectors[o] + acc_ws[NS + o] + acc;
    }
}

extern "C" void kernel_launch(void* const* d_in, const int* in_sizes, int n_in,
                              void* d_out, int out_size, void* d_ws, size_t ws_size,
                              hipStream_t stream)
{
    const float* scalars  = (const float*)d_in[0];
    const float* vectors  = (const float*)d_in[1];
    const float* edge_vec = (const float*)d_in[2];
    const float* W1  = (const float*)d_in[3];
    const float* b1  = (const float*)d_in[4];
    const float* W2  = (const float*)d_in[5];
    const float* b2  = (const float*)d_in[6];
    const float* Wa1 = (const float*)d_in[7];
    const float* ba1 = (const float*)d_in[8];
    const float* Wa2 = (const float*)d_in[9];
    const float* ba2 = (const float*)d_in[10];
    const int* eidx  = (const int*)d_in[11];

    char* wsb = (char*)d_ws;
    // layout (192.6 MB total — below the 215.6 MB proven by rounds 3-13):
    // Fhalf(EH x 96 f16) | attsh(E f4) | P1 | P2 | acc(NS+NV f32) | cnt | bsum | boff | row_start | perm | srcbuf | tbl | tbl2
    _Float16* Fg  = (_Float16*)wsb;                        // 122.88 MB
    float4* attsh = (float4*)(wsb + (size_t)EH * 192);     // 20.48 MB
    float*  P1    = (float*)((char*)attsh + (size_t)E_ * 16);
    float*  P2    = P1 + NS;
    float*  acc   = P2 + NS;                               // NS+NV floats = 17.92 MB
    int* cnt       = (int*)(acc + NS + NV);                // N
    int* bsum      = cnt + N_;                             // 40 (pad 64)
    int* boff      = bsum + 64;                            // 40 (pad 64)
    int* row_start = cnt + 2 * N_;                         // N+1
    int* perm      = row_start + N_ + 1;                   // E
    int* srcbuf    = perm + E_;                            // E
    uint* tbl      = (uint*)(srcbuf + E_);                 // 1536
    uint* tbl2     = tbl + 1536;                           // 1536
    int*  rnk      = (int*)Fg;                             // aliases F half (dead after k_place)

    hipMemsetAsync(cnt, 0, (size_t)N_ * sizeof(int), stream);
    k_pack<<<12, 256, 0, stream>>>(W1, Wa1, W2, tbl, tbl2);
    k_rank<<<5000, 256, 0, stream>>>(eidx, cnt, rnk);
    k_scan1<<<40, 1024, 0, stream>>>(cnt, row_start, bsum);
    k_scan2<<<1, 64, 0, stream>>>(bsum, boff);
    k_scan3<<<40, 1024, 0, stream>>>(boff, row_start);
    k_place<<<5000, 256, 0, stream>>>(eidx, row_start, rnk, perm);
    k_precompute<<<10000, 256, 0, stream>>>(scalars, Wa1, ba1, P1, P2);

    // pass 0: slots [0, EH)
    k_edges_F<<<2500, 256, 0, stream>>>(edge_vec, eidx, perm, P1, P2, tbl, tbl2,
                                        b1, Wa2, ba2, attsh, srcbuf, Fg, 0);
    k_gather_F<0><<<20000, 256, 0, stream>>>(scalars, vectors, b2, row_start,
                                             attsh, srcbuf, Fg, 0, EH, acc,
                                             (float*)d_out);
    // pass 1: slots [EH, E)
    k_edges_F<<<2500, 256, 0, stream>>>(edge_vec, eidx, perm, P1, P2, tbl, tbl2,
                                        b1, Wa2, ba2, attsh, srcbuf, Fg, EH);
    k_gather_F<1><<<20000, 256, 0, stream>>>(scalars, vectors, b2, row_start,
                                             attsh, srcbuf, Fg, EH, E_, acc,
                                             (float*)d_out);
}

// Round 15
// 474.027 us; speedup vs baseline: 1.2242x; 1.2242x over previous
//
#include <hip/hip_runtime.h>

static constexpr int N_ = 40000;
static constexpr int E_ = 1280000;
static constexpr int NS = N_ * 64;      // 2,560,000 scalar elems
static constexpr int NV = N_ * 48;      // 1,920,000 vector elems

typedef _Float16 half2_t __attribute__((ext_vector_type(2)));
typedef _Float16 half8_t __attribute__((ext_vector_type(8)));
typedef float float4_t __attribute__((ext_vector_type(4)));
typedef unsigned int uint;

__device__ __forceinline__ float silu_f(float x) { return __fdividef(x, 1.f + __expf(-x)); }
__device__ __forceinline__ int rfl(int x) { return __builtin_amdgcn_readfirstlane(x); }

// ---- per-node attention precompute (proven r3+) ----
__global__ void k_precompute(const float* __restrict__ scalars, const float* __restrict__ Wa1,
                             const float* __restrict__ ba1,
                             float* __restrict__ P1, float* __restrict__ P2)
{
    int t = blockIdx.x * 256 + threadIdx.x;  // t < N*64
    int n = t >> 6, j = t & 63;
    float a1 = ba1[j];
    float a2 = 0.f;
    const float* srow = scalars + (size_t)n * 64;
#pragma unroll 8
    for (int k = 0; k < 64; k++) {
        float s = srow[k];
        a1 = fmaf(s, Wa1[k * 64 + j], a1);
        a2 = fmaf(s, Wa1[(64 + k) * 64 + j], a2);
    }
    P1[t] = a1;
    P2[t] = a2;
}

// ---- pack MFMA B tables (proven r13/r14): tbl = [Wa1_att|W1], tbl2 = W2 ----
__global__ void k_pack(const float* __restrict__ W1, const float* __restrict__ Wa1,
                       const float* __restrict__ W2, uint* __restrict__ tbl,
                       uint* __restrict__ tbl2)
{
    int t = blockIdx.x * 256 + threadIdx.x;
    if (t < 1536) {
        int j = t >> 4, q = t & 15;
        int k0 = 2 * q, k1 = 2 * q + 1;
        float a = (j < 64) ? Wa1[(128 + k0) * 64 + j] : W1[k0 * 32 + (j - 64)];
        float b = (j < 64) ? Wa1[(128 + k1) * 64 + j] : W1[k1 * 32 + (j - 64)];
        half2_t v; v.x = (_Float16)a; v.y = (_Float16)b;
        tbl[t] = __builtin_bit_cast(uint, v);
    } else if (t < 3072) {
        int tt = t - 1536;
        int j = tt >> 4, q = tt & 15;
        half2_t v;
        v.x = (_Float16)W2[(2 * q + 0) * 96 + j];
        v.y = (_Float16)W2[(2 * q + 1) * 96 + j];
        tbl2[tt] = __builtin_bit_cast(uint, v);
    }
}

// ================= CSR build (round-9 proven) =================
__global__ void k_rank(const int* __restrict__ eidx, int* __restrict__ cnt,
                       int* __restrict__ r)
{
    int e = blockIdx.x * 256 + threadIdx.x;
    r[e] = atomicAdd(&cnt[eidx[E_ + e]], 1);
}

__global__ void k_scan1(const int* __restrict__ cnt, int* __restrict__ row_start,
                        int* __restrict__ bsum)
{
    __shared__ int buf[1024];
    int b = blockIdx.x, tid = threadIdx.x;
    int idx = b * 1024 + tid;
    int v = (idx < N_) ? cnt[idx] : 0;
    buf[tid] = v;
    __syncthreads();
    for (int off = 1; off < 1024; off <<= 1) {
        int t = (tid >= off) ? buf[tid - off] : 0;
        __syncthreads();
        buf[tid] += t;
        __syncthreads();
    }
    if (idx < N_) row_start[idx] = buf[tid] - v;
    if (tid == 1023) bsum[b] = buf[1023];
}

__global__ void k_scan2(const int* __restrict__ bsum, int* __restrict__ boff)
{
    if (threadIdx.x == 0) {
        int s = 0;
        for (int b = 0; b < 40; b++) { boff[b] = s; s += bsum[b]; }
    }
}

__global__ void k_scan3(const int* __restrict__ boff, int* __restrict__ row_start)
{
    int idx = blockIdx.x * 1024 + threadIdx.x;
    if (idx < N_) row_start[idx] += boff[blockIdx.x];
    if (idx == N_) row_start[N_] = E_;
}

__global__ void k_place(const int* __restrict__ eidx, const int* __restrict__ row_start,
                        const int* __restrict__ r, int* __restrict__ perm)
{
    int e = blockIdx.x * 256 + threadIdx.x;
    int dst = eidx[E_ + e];
    perm[row_start[dst] + r[e]] = e;
}

// ================= edge phase (round-12 proven, byte-identical) =================
__global__ __launch_bounds__(256, 3) void k_edges_sorted(
    const float* __restrict__ edge_vec, const int* __restrict__ eidx,
    const int* __restrict__ perm,
    const float* __restrict__ P1, const float* __restrict__ P2,
    const uint* __restrict__ tbl, const float* __restrict__ b1,
    const float* __restrict__ Wa2, const float* __restrict__ ba2,
    float4* __restrict__ attsh, int* __restrict__ srcbuf, uint* __restrict__ hbufp)
{
    __shared__ char lds_raw[4 * 12544];
    int tid = threadIdx.x;
    int wid = tid >> 6, lane = tid & 63;
    char* wbase = lds_raw + wid * 12544;
    int bl = lane & 15, bq = lane >> 4;

    int i = blockIdx.x * 256 + tid;
    int e = perm[i];
    int src = eidx[e];
    int dst = eidx[E_ + e];

    float ev0 = edge_vec[3 * e + 0];
    float ev1 = edge_vec[3 * e + 1];
    float ev2 = edge_vec[3 * e + 2];
    float d = sqrtf(fmaf(ev0, ev0, fmaf(ev1, ev1, ev2 * ev2)));
    float inv_d = __fdividef(1.f, fmaxf(d, 1e-8f));
    float cut = (d < 10.f) ? 0.5f * (__cosf(0.31415927f * d) + 1.f) : 0.f;
    float cutd = cut * inv_d;
    float sh0 = ev1 * inv_d, sh1 = ev2 * inv_d, sh2 = ev0 * inv_d;

    uint rbf2[16];
#pragma unroll
    for (int q = 0; q < 16; q++) {
        float r0 = __sinf((float)(2 * q + 1) * 0.31415927f * d) * cutd;
        float r1 = __sinf((float)(2 * q + 2) * 0.31415927f * d) * cutd;
        half2_t v; v.x = (_Float16)r0; v.y = (_Float16)r1;
        rbf2[q] = __builtin_bit_cast(uint, v);
    }
    {
        uint4* rw = (uint4*)(wbase + lane * 64);
        rw[0] = make_uint4(rbf2[0], rbf2[1], rbf2[2], rbf2[3]);
        rw[1] = make_uint4(rbf2[4], rbf2[5], rbf2[6], rbf2[7]);
        rw[2] = make_uint4(rbf2[8], rbf2[9], rbf2[10], rbf2[11]);
        rw[3] = make_uint4(rbf2[12], rbf2[13], rbf2[14], rbf2[15]);
    }
    uint4 bfr[6];
#pragma unroll
    for (int u = 0; u < 6; u++)
        bfr[u] = *(const uint4*)(tbl + (u * 16 + bl) * 16 + bq * 4);
    __syncthreads();
    uint4 afr[4];
#pragma unroll
    for (int t = 0; t < 4; t++)
        afr[t] = *(const uint4*)(wbase + (t * 16 + bl) * 64 + bq * 16);
    __syncthreads();
    _Float16* gtile = (_Float16*)wbase;
#pragma unroll
    for (int t = 0; t < 4; t++) {
        half8_t av = __builtin_bit_cast(half8_t, afr[t]);
        int eb = t * 16 + bq * 4;
#pragma unroll
        for (int u = 0; u < 6; u++) {
            float4_t dd = __builtin_amdgcn_mfma_f32_16x16x32_f16(
                av, __builtin_bit_cast(half8_t, bfr[u]), (float4_t)(0.f), 0, 0, 0);
            int col = u * 16 + bl;
            gtile[(eb + 0) * 98 + col] = (_Float16)dd[0];
            gtile[(eb + 1) * 98 + col] = (_Float16)dd[1];
            gtile[(eb + 2) * 98 + col] = (_Float16)dd[2];
            gtile[(eb + 3) * 98 + col] = (_Float16)dd[3];
        }
    }
    __syncthreads();
    const uint* grow = (const uint*)(wbase + (size_t)lane * 196);
    const float4* p14 = (const float4*)(P1 + (size_t)dst * 64);
    const float4* p24 = (const float4*)(P2 + (size_t)src * 64);
    float logit = ba2[0];
#pragma unroll
    for (int q = 0; q < 16; q++) {
        float4 a = p14[q];
        float4 b = p24[q];
        half2_t g01 = __builtin_bit_cast(half2_t, grow[2 * q + 0]);
        half2_t g23 = __builtin_bit_cast(half2_t, grow[2 * q + 1]);
        logit = fmaf(silu_f(a.x + b.x + (float)g01.x), Wa2[4 * q + 0], logit);
        logit = fmaf(silu_f(a.y + b.y + (float)g01.y), Wa2[4 * q + 1], logit);
        logit = fmaf(silu_f(a.z + b.z + (float)g23.x), Wa2[4 * q + 2], logit);
        logit = fmaf(silu_f(a.w + b.w + (float)g23.y), Wa2[4 * q + 3], logit);
    }
    float att = __fdividef(1.f, 1.f + __expf(-logit));
    uint hp[16];
#pragma unroll
    for (int q = 0; q < 16; q++) {
        half2_t gg = __builtin_bit_cast(half2_t, grow[32 + q]);
        half2_t v;
        v.x = (_Float16)silu_f((float)gg.x + b1[2 * q + 0]);
        v.y = (_Float16)silu_f((float)gg.y + b1[2 * q + 1]);
        hp[q] = __builtin_bit_cast(uint, v);
    }
    uint4* hrow4 = (uint4*)(hbufp + (size_t)i * 16);
#pragma unroll
    for (int q = 0; q < 4; q++)
        hrow4[q] = make_uint4(hp[4 * q + 0], hp[4 * q + 1], hp[4 * q + 2], hp[4 * q + 3]);
    attsh[i] = make_float4(att, sh0, sh1, sh2);
    srcbuf[i] = src;
}

// ================= NEW gather: wave-per-node, F = h@W2 via MFMA straight from hbuf ==========
// hbuf's 64 B k-pair rows ARE the A-fragment layout: lane(bl,bq) loads uint4 at
// (i0+bl)*16 + bq*4 — coalesced, no LDS, no barriers. D: lane holds F[edge bq*4+r][u*16+bl].
__global__ __launch_bounds__(256, 4) void k_gather_mfma(
    const float* __restrict__ scalars, const float* __restrict__ vectors,
    const float* __restrict__ b2,
    const int* __restrict__ row_start,
    const float4* __restrict__ attsh, const int* __restrict__ srcbuf,
    const uint* __restrict__ hbuf, const uint* __restrict__ tbl2,
    float* __restrict__ out)
{
    int wid  = threadIdx.x >> 6;
    int lane = threadIdx.x & 63;
    int n    = blockIdx.x * 4 + wid;
    int bl = lane & 15, bq = lane >> 4;
    int rs = rfl(row_start[n]);
    int re = rfl(row_start[n + 1]);

    uint4 bfr2[6];
#pragma unroll
    for (int u = 0; u < 6; u++)
        bfr2[u] = *(const uint4*)(tbl2 + (u * 16 + bl) * 16 + bq * 4);

    float b2s[4];
#pragma unroll
    for (int u = 0; u < 4; u++) b2s[u] = b2[u * 16 + bl];
    float bvf = b2[64 + bl], bvg = b2[80 + bl];

    float accS0 = 0.f, accS1 = 0.f, accS2 = 0.f, accS3 = 0.f;
    float accV0 = 0.f, accV1 = 0.f, accV2 = 0.f;

    for (int i0 = rs; i0 < re; i0 += 16) {
        // A-fragment: h row i0+bl (exec-masked; invalid rows contribute zero F)
        uint4 av4 = make_uint4(0u, 0u, 0u, 0u);
        if (i0 + bl < re)
            av4 = *(const uint4*)(hbuf + (size_t)(i0 + bl) * 16 + bq * 4);
        half8_t av = __builtin_bit_cast(half8_t, av4);

        float4_t d0 = __builtin_amdgcn_mfma_f32_16x16x32_f16(av, __builtin_bit_cast(half8_t, bfr2[0]), (float4_t)(0.f), 0, 0, 0);
        float4_t d1 = __builtin_amdgcn_mfma_f32_16x16x32_f16(av, __builtin_bit_cast(half8_t, bfr2[1]), (float4_t)(0.f), 0, 0, 0);
        float4_t d2 = __builtin_amdgcn_mfma_f32_16x16x32_f16(av, __builtin_bit_cast(half8_t, bfr2[2]), (float4_t)(0.f), 0, 0, 0);
        float4_t d3 = __builtin_amdgcn_mfma_f32_16x16x32_f16(av, __builtin_bit_cast(half8_t, bfr2[3]), (float4_t)(0.f), 0, 0, 0);
        float4_t d4 = __builtin_amdgcn_mfma_f32_16x16x32_f16(av, __builtin_bit_cast(half8_t, bfr2[4]), (float4_t)(0.f), 0, 0, 0);
        float4_t d5 = __builtin_amdgcn_mfma_f32_16x16x32_f16(av, __builtin_bit_cast(half8_t, bfr2[5]), (float4_t)(0.f), 0, 0, 0);

#pragma unroll
        for (int r = 0; r < 4; r++) {
            int slot = i0 + bq * 4 + r;
            int ok = (slot < re);
            int cs = ok ? slot : (re - 1);       // re >= 1 inside the loop
            float4 as = attsh[cs];
            float att = ok ? as.x : 0.f;
            int src = srcbuf[cs];
            const float* srow = scalars + (size_t)src * 64 + bl;
            accS0 = fmaf(att * srow[0],  d0[r] + b2s[0], accS0);
            accS1 = fmaf(att * srow[16], d1[r] + b2s[1], accS1);
            accS2 = fmaf(att * srow[32], d2[r] + b2s[2], accS2);
            accS3 = fmaf(att * srow[48], d3[r] + b2s[3], accS3);
            float vf = d4[r] + bvf;
            float vg = d5[r] + bvg;
            const float* vr = vectors + (size_t)src * 48 + 3 * bl;
            accV0 = fmaf(att, fmaf(vr[0], vf, vg * as.y), accV0);
            accV1 = fmaf(att, fmaf(vr[1], vf, vg * as.z), accV1);
            accV2 = fmaf(att, fmaf(vr[2], vf, vg * as.w), accV2);
        }
    }

    // butterfly-reduce across the 4 bq groups (partners differ only in bq bits)
    accS0 += __shfl_xor(accS0, 16, 64); accS0 += __shfl_xor(accS0, 32, 64);
    accS1 += __shfl_xor(accS1, 16, 64); accS1 += __shfl_xor(accS1, 32, 64);
    accS2 += __shfl_xor(accS2, 16, 64); accS2 += __shfl_xor(accS2, 32, 64);
    accS3 += __shfl_xor(accS3, 16, 64); accS3 += __shfl_xor(accS3, 32, 64);
    accV0 += __shfl_xor(accV0, 16, 64); accV0 += __shfl_xor(accV0, 32, 64);
    accV1 += __shfl_xor(accV1, 16, 64); accV1 += __shfl_xor(accV1, 32, 64);
    accV2 += __shfl_xor(accV2, 16, 64); accV2 += __shfl_xor(accV2, 32, 64);

    if (bq == 0) {   // lanes 0-15 write
        size_t o = (size_t)n * 64 + bl;
        out[o +  0] = scalars[o +  0] + accS0;
        out[o + 16] = scalars[o + 16] + accS1;
        out[o + 32] = scalars[o + 32] + accS2;
        out[o + 48] = scalars[o + 48] + accS3;
        size_t ov = (size_t)n * 48 + 3 * bl;
        out[NS + ov + 0] = vectors[ov + 0] + accV0;
        out[NS + ov + 1] = vectors[ov + 1] + accV1;
        out[NS + ov + 2] = vectors[ov + 2] + accV2;
    }
}

extern "C" void kernel_launch(void* const* d_in, const int* in_sizes, int n_in,
                              void* d_out, int out_size, void* d_ws, size_t ws_size,
                              hipStream_t stream)
{
    const float* scalars  = (const float*)d_in[0];
    const float* vectors  = (const float*)d_in[1];
    const float* edge_vec = (const float*)d_in[2];
    const float* W1  = (const float*)d_in[3];
    const float* b1  = (const float*)d_in[4];
    const float* W2  = (const float*)d_in[5];
    const float* b2  = (const float*)d_in[6];
    const float* Wa1 = (const float*)d_in[7];
    const float* ba1 = (const float*)d_in[8];
    const float* Wa2 = (const float*)d_in[9];
    const float* ba2 = (const float*)d_in[10];
    const int* eidx  = (const int*)d_in[11];

    char* wsb = (char*)d_ws;
    // round-12/13-fallback proven layout (~215.6 MB): attsh | P1 | P2 | hbuf(region) | ints
    float4* attsh = (float4*)wsb;                       // E float4      = 20.48 MB
    float*  P1    = (float*)(wsb + (size_t)E_ * 16);    // NS floats
    float*  P2    = P1 + NS;                            // NS floats
    float*  hbuf  = P2 + NS;                            // region: 32E floats = 163.84 MB
    int* cnt       = (int*)(hbuf + (size_t)32 * E_);    // N
    int* bsum      = cnt + N_;                          // 40
    int* boff      = bsum + 64;                         // 40
    int* row_start = cnt + 2 * N_;                      // N+1
    int* perm      = row_start + N_ + 1;                // E
    int* srcbuf    = perm + E_;                         // E
    int*  rnk  = (int*)hbuf;                            // aliases hbuf region (dead after k_place)
    uint* tbl  = (uint*)hbuf + (size_t)16 * E_;         // 1536 (tail of hbuf region)
    uint* tbl2 = tbl + 1536;                            // 1536

    hipMemsetAsync(cnt, 0, (size_t)N_ * sizeof(int), stream);
    k_pack<<<12, 256, 0, stream>>>(W1, Wa1, W2, tbl, tbl2);
    k_rank<<<5000, 256, 0, stream>>>(eidx, cnt, rnk);
    k_scan1<<<40, 1024, 0, stream>>>(cnt, row_start, bsum);
    k_scan2<<<1, 64, 0, stream>>>(bsum, boff);
    k_scan3<<<40, 1024, 0, stream>>>(boff, row_start);
    k_place<<<5000, 256, 0, stream>>>(eidx, row_start, rnk, perm);
    k_precompute<<<10000, 256, 0, stream>>>(scalars, Wa1, ba1, P1, P2);
    k_edges_sorted<<<5000, 256, 0, stream>>>(edge_vec, eidx, perm, P1, P2,
                                             tbl, b1, Wa2, ba2,
                                             attsh, srcbuf, (uint*)hbuf);
    k_gather_mfma<<<10000, 256, 0, stream>>>(scalars, vectors, b2, row_start,
                                             attsh, srcbuf, (const uint*)hbuf, tbl2,
                                             (float*)d_out);
}

// Round 16
// 453.322 us; speedup vs baseline: 1.2801x; 1.0457x over previous
//
#include <hip/hip_runtime.h>

static constexpr int N_ = 40000;
static constexpr int E_ = 1280000;
static constexpr int NS = N_ * 64;      // 2,560,000 scalar elems
static constexpr int NV = N_ * 48;      // 1,920,000 vector elems

typedef _Float16 half2_t __attribute__((ext_vector_type(2)));
typedef _Float16 half8_t __attribute__((ext_vector_type(8)));
typedef float float4_t __attribute__((ext_vector_type(4)));
typedef unsigned int uint;

__device__ __forceinline__ float silu_f(float x) { return __fdividef(x, 1.f + __expf(-x)); }
__device__ __forceinline__ int rfl(int x) { return __builtin_amdgcn_readfirstlane(x); }

// ---- per-node attention precompute -> f16 rows (128 B/row gathered later) ----
__global__ void k_precompute(const float* __restrict__ scalars, const float* __restrict__ Wa1,
                             const float* __restrict__ ba1,
                             _Float16* __restrict__ P1h, _Float16* __restrict__ P2h)
{
    int t = blockIdx.x * 256 + threadIdx.x;  // t < N*64
    int n = t >> 6, j = t & 63;
    float a1 = ba1[j];
    float a2 = 0.f;
    const float* srow = scalars + (size_t)n * 64;
#pragma unroll 8
    for (int k = 0; k < 64; k++) {
        float s = srow[k];
        a1 = fmaf(s, Wa1[k * 64 + j], a1);
        a2 = fmaf(s, Wa1[(64 + k) * 64 + j], a2);
    }
    P1h[t] = (_Float16)a1;
    P2h[t] = (_Float16)a2;
}

// ---- f16 copies of the gather tables ----
__global__ void k_convert(const float* __restrict__ scalars, const float* __restrict__ vectors,
                          _Float16* __restrict__ sc16, _Float16* __restrict__ vec16)
{
    int t = blockIdx.x * 256 + threadIdx.x;   // 17500*256 = NS+NV exactly
    if (t < NS) sc16[t] = (_Float16)scalars[t];
    else        vec16[t - NS] = (_Float16)vectors[t - NS];
}

// ---- pack MFMA B tables (proven r13/r14): tbl = [Wa1_att|W1], tbl2 = W2 ----
__global__ void k_pack(const float* __restrict__ W1, const float* __restrict__ Wa1,
                       const float* __restrict__ W2, uint* __restrict__ tbl,
                       uint* __restrict__ tbl2)
{
    int t = blockIdx.x * 256 + threadIdx.x;
    if (t < 1536) {
        int j = t >> 4, q = t & 15;
        int k0 = 2 * q, k1 = 2 * q + 1;
        float a = (j < 64) ? Wa1[(128 + k0) * 64 + j] : W1[k0 * 32 + (j - 64)];
        float b = (j < 64) ? Wa1[(128 + k1) * 64 + j] : W1[k1 * 32 + (j - 64)];
        half2_t v; v.x = (_Float16)a; v.y = (_Float16)b;
        tbl[t] = __builtin_bit_cast(uint, v);
    } else if (t < 3072) {
        int tt = t - 1536;
        int j = tt >> 4, q = tt & 15;
        half2_t v;
        v.x = (_Float16)W2[(2 * q + 0) * 96 + j];
        v.y = (_Float16)W2[(2 * q + 1) * 96 + j];
        tbl2[tt] = __builtin_bit_cast(uint, v);
    }
}

// ================= CSR build (round-9 proven) =================
__global__ void k_rank(const int* __restrict__ eidx, int* __restrict__ cnt,
                       int* __restrict__ r)
{
    int e = blockIdx.x * 256 + threadIdx.x;
    r[e] = atomicAdd(&cnt[eidx[E_ + e]], 1);
}

__global__ void k_scan1(const int* __restrict__ cnt, int* __restrict__ row_start,
                        int* __restrict__ bsum)
{
    __shared__ int buf[1024];
    int b = blockIdx.x, tid = threadIdx.x;
    int idx = b * 1024 + tid;
    int v = (idx < N_) ? cnt[idx] : 0;
    buf[tid] = v;
    __syncthreads();
    for (int off = 1; off < 1024; off <<= 1) {
        int t = (tid >= off) ? buf[tid - off] : 0;
        __syncthreads();
        buf[tid] += t;
        __syncthreads();
    }
    if (idx < N_) row_start[idx] = buf[tid] - v;
    if (tid == 1023) bsum[b] = buf[1023];
}

__global__ void k_scan2(const int* __restrict__ bsum, int* __restrict__ boff)
{
    if (threadIdx.x == 0) {
        int s = 0;
        for (int b = 0; b < 40; b++) { boff[b] = s; s += bsum[b]; }
    }
}

__global__ void k_scan3(const int* __restrict__ boff, int* __restrict__ row_start)
{
    int idx = blockIdx.x * 1024 + threadIdx.x;
    if (idx < N_) row_start[idx] += boff[blockIdx.x];
    if (idx == N_) row_start[N_] = E_;
}

__global__ void k_place(const int* __restrict__ eidx, const int* __restrict__ row_start,
                        const int* __restrict__ r, int* __restrict__ perm)
{
    int e = blockIdx.x * 256 + threadIdx.x;
    int dst = eidx[E_ + e];
    perm[row_start[dst] + r[e]] = e;
}

// ================= edge phase: vs r15, ONLY P1/P2 loads change (f16 rows) =================
__global__ __launch_bounds__(256, 3) void k_edges_sorted(
    const float* __restrict__ edge_vec, const int* __restrict__ eidx,
    const int* __restrict__ perm,
    const _Float16* __restrict__ P1h, const _Float16* __restrict__ P2h,
    const uint* __restrict__ tbl, const float* __restrict__ b1,
    const float* __restrict__ Wa2, const float* __restrict__ ba2,
    float4* __restrict__ attsh, int* __restrict__ srcbuf, uint* __restrict__ hbufp)
{
    __shared__ char lds_raw[4 * 12544];
    int tid = threadIdx.x;
    int wid = tid >> 6, lane = tid & 63;
    char* wbase = lds_raw + wid * 12544;
    int bl = lane & 15, bq = lane >> 4;

    int i = blockIdx.x * 256 + tid;
    int e = perm[i];
    int src = eidx[e];
    int dst = eidx[E_ + e];

    float ev0 = edge_vec[3 * e + 0];
    float ev1 = edge_vec[3 * e + 1];
    float ev2 = edge_vec[3 * e + 2];
    float d = sqrtf(fmaf(ev0, ev0, fmaf(ev1, ev1, ev2 * ev2)));
    float inv_d = __fdividef(1.f, fmaxf(d, 1e-8f));
    float cut = (d < 10.f) ? 0.5f * (__cosf(0.31415927f * d) + 1.f) : 0.f;
    float cutd = cut * inv_d;
    float sh0 = ev1 * inv_d, sh1 = ev2 * inv_d, sh2 = ev0 * inv_d;

    uint rbf2[16];
#pragma unroll
    for (int q = 0; q < 16; q++) {
        float r0 = __sinf((float)(2 * q + 1) * 0.31415927f * d) * cutd;
        float r1 = __sinf((float)(2 * q + 2) * 0.31415927f * d) * cutd;
        half2_t v; v.x = (_Float16)r0; v.y = (_Float16)r1;
        rbf2[q] = __builtin_bit_cast(uint, v);
    }
    {
        uint4* rw = (uint4*)(wbase + lane * 64);
        rw[0] = make_uint4(rbf2[0], rbf2[1], rbf2[2], rbf2[3]);
        rw[1] = make_uint4(rbf2[4], rbf2[5], rbf2[6], rbf2[7]);
        rw[2] = make_uint4(rbf2[8], rbf2[9], rbf2[10], rbf2[11]);
        rw[3] = make_uint4(rbf2[12], rbf2[13], rbf2[14], rbf2[15]);
    }
    uint4 bfr[6];
#pragma unroll
    for (int u = 0; u < 6; u++)
        bfr[u] = *(const uint4*)(tbl + (u * 16 + bl) * 16 + bq * 4);
    __syncthreads();
    uint4 afr[4];
#pragma unroll
    for (int t = 0; t < 4; t++)
        afr[t] = *(const uint4*)(wbase + (t * 16 + bl) * 64 + bq * 16);
    __syncthreads();
    _Float16* gtile = (_Float16*)wbase;
#pragma unroll
    for (int t = 0; t < 4; t++) {
        half8_t av = __builtin_bit_cast(half8_t, afr[t]);
        int eb = t * 16 + bq * 4;
#pragma unroll
        for (int u = 0; u < 6; u++) {
            float4_t dd = __builtin_amdgcn_mfma_f32_16x16x32_f16(
                av, __builtin_bit_cast(half8_t, bfr[u]), (float4_t)(0.f), 0, 0, 0);
            int col = u * 16 + bl;
            gtile[(eb + 0) * 98 + col] = (_Float16)dd[0];
            gtile[(eb + 1) * 98 + col] = (_Float16)dd[1];
            gtile[(eb + 2) * 98 + col] = (_Float16)dd[2];
            gtile[(eb + 3) * 98 + col] = (_Float16)dd[3];
        }
    }
    __syncthreads();
    const uint* grow = (const uint*)(wbase + (size_t)lane * 196);

    const uint2* p1h = (const uint2*)(P1h + (size_t)dst * 64);   // 8B = 4 halves per q
    const uint2* p2h = (const uint2*)(P2h + (size_t)src * 64);
    float logit = ba2[0];
#pragma unroll
    for (int q = 0; q < 16; q++) {
        uint2 ua = p1h[q];
        uint2 ub = p2h[q];
        half2_t a01 = __builtin_bit_cast(half2_t, ua.x);
        half2_t a23 = __builtin_bit_cast(half2_t, ua.y);
        half2_t b01 = __builtin_bit_cast(half2_t, ub.x);
        half2_t b23 = __builtin_bit_cast(half2_t, ub.y);
        half2_t g01 = __builtin_bit_cast(half2_t, grow[2 * q + 0]);
        half2_t g23 = __builtin_bit_cast(half2_t, grow[2 * q + 1]);
        logit = fmaf(silu_f((float)a01.x + (float)b01.x + (float)g01.x), Wa2[4 * q + 0], logit);
        logit = fmaf(silu_f((float)a01.y + (float)b01.y + (float)g01.y), Wa2[4 * q + 1], logit);
        logit = fmaf(silu_f((float)a23.x + (float)b23.x + (float)g23.x), Wa2[4 * q + 2], logit);
        logit = fmaf(silu_f((float)a23.y + (float)b23.y + (float)g23.y), Wa2[4 * q + 3], logit);
    }
    float att = __fdividef(1.f, 1.f + __expf(-logit));

    uint hp[16];
#pragma unroll
    for (int q = 0; q < 16; q++) {
        half2_t gg = __builtin_bit_cast(half2_t, grow[32 + q]);
        half2_t v;
        v.x = (_Float16)silu_f((float)gg.x + b1[2 * q + 0]);
        v.y = (_Float16)silu_f((float)gg.y + b1[2 * q + 1]);
        hp[q] = __builtin_bit_cast(uint, v);
    }
    uint4* hrow4 = (uint4*)(hbufp + (size_t)i * 16);
#pragma unroll
    for (int q = 0; q < 4; q++)
        hrow4[q] = make_uint4(hp[4 * q + 0], hp[4 * q + 1], hp[4 * q + 2], hp[4 * q + 3]);
    attsh[i] = make_float4(att, sh0, sh1, sh2);
    srcbuf[i] = src;
}

// ================= gather (r15 proven structure): vs r15, ONLY s/v gathers -> f16 tables =====
__global__ __launch_bounds__(256, 4) void k_gather_mfma(
    const float* __restrict__ scalars, const float* __restrict__ vectors,
    const _Float16* __restrict__ sc16, const _Float16* __restrict__ vec16,
    const float* __restrict__ b2,
    const int* __restrict__ row_start,
    const float4* __restrict__ attsh, const int* __restrict__ srcbuf,
    const uint* __restrict__ hbuf, const uint* __restrict__ tbl2,
    float* __restrict__ out)
{
    int wid  = threadIdx.x >> 6;
    int lane = threadIdx.x & 63;
    int n    = blockIdx.x * 4 + wid;
    int bl = lane & 15, bq = lane >> 4;
    int rs = rfl(row_start[n]);
    int re = rfl(row_start[n + 1]);

    uint4 bfr2[6];
#pragma unroll
    for (int u = 0; u < 6; u++)
        bfr2[u] = *(const uint4*)(tbl2 + (u * 16 + bl) * 16 + bq * 4);

    float b2s[4];
#pragma unroll
    for (int u = 0; u < 4; u++) b2s[u] = b2[u * 16 + bl];
    float bvf = b2[64 + bl], bvg = b2[80 + bl];

    float accS0 = 0.f, accS1 = 0.f, accS2 = 0.f, accS3 = 0.f;
    float accV0 = 0.f, accV1 = 0.f, accV2 = 0.f;

    for (int i0 = rs; i0 < re; i0 += 16) {
        uint4 av4 = make_uint4(0u, 0u, 0u, 0u);
        if (i0 + bl < re)
            av4 = *(const uint4*)(hbuf + (size_t)(i0 + bl) * 16 + bq * 4);
        half8_t av = __builtin_bit_cast(half8_t, av4);

        float4_t d0 = __builtin_amdgcn_mfma_f32_16x16x32_f16(av, __builtin_bit_cast(half8_t, bfr2[0]), (float4_t)(0.f), 0, 0, 0);
        float4_t d1 = __builtin_amdgcn_mfma_f32_16x16x32_f16(av, __builtin_bit_cast(half8_t, bfr2[1]), (float4_t)(0.f), 0, 0, 0);
        float4_t d2 = __builtin_amdgcn_mfma_f32_16x16x32_f16(av, __builtin_bit_cast(half8_t, bfr2[2]), (float4_t)(0.f), 0, 0, 0);
        float4_t d3 = __builtin_amdgcn_mfma_f32_16x16x32_f16(av, __builtin_bit_cast(half8_t, bfr2[3]), (float4_t)(0.f), 0, 0, 0);
        float4_t d4 = __builtin_amdgcn_mfma_f32_16x16x32_f16(av, __builtin_bit_cast(half8_t, bfr2[4]), (float4_t)(0.f), 0, 0, 0);
        float4_t d5 = __builtin_amdgcn_mfma_f32_16x16x32_f16(av, __builtin_bit_cast(half8_t, bfr2[5]), (float4_t)(0.f), 0, 0, 0);

#pragma unroll
        for (int r = 0; r < 4; r++) {
            int slot = i0 + bq * 4 + r;
            int ok = (slot < re);
            int cs = ok ? slot : (re - 1);
            float4 as = attsh[cs];
            float att = ok ? as.x : 0.f;
            int src = srcbuf[cs];
            const _Float16* srow = sc16 + (size_t)src * 64 + bl;
            accS0 = fmaf(att * (float)srow[0],  d0[r] + b2s[0], accS0);
            accS1 = fmaf(att * (float)srow[16], d1[r] + b2s[1], accS1);
            accS2 = fmaf(att * (float)srow[32], d2[r] + b2s[2], accS2);
            accS3 = fmaf(att * (float)srow[48], d3[r] + b2s[3], accS3);
            float vf = d4[r] + bvf;
            float vg = d5[r] + bvg;
            const _Float16* vr = vec16 + (size_t)src * 48 + 3 * bl;
            accV0 = fmaf(att, fmaf((float)vr[0], vf, vg * as.y), accV0);
            accV1 = fmaf(att, fmaf((float)vr[1], vf, vg * as.z), accV1);
            accV2 = fmaf(att, fmaf((float)vr[2], vf, vg * as.w), accV2);
        }
    }

    accS0 += __shfl_xor(accS0, 16, 64); accS0 += __shfl_xor(accS0, 32, 64);
    accS1 += __shfl_xor(accS1, 16, 64); accS1 += __shfl_xor(accS1, 32, 64);
    accS2 += __shfl_xor(accS2, 16, 64); accS2 += __shfl_xor(accS2, 32, 64);
    accS3 += __shfl_xor(accS3, 16, 64); accS3 += __shfl_xor(accS3, 32, 64);
    accV0 += __shfl_xor(accV0, 16, 64); accV0 += __shfl_xor(accV0, 32, 64);
    accV1 += __shfl_xor(accV1, 16, 64); accV1 += __shfl_xor(accV1, 32, 64);
    accV2 += __shfl_xor(accV2, 16, 64); accV2 += __shfl_xor(accV2, 32, 64);

    if (bq == 0) {
        size_t o = (size_t)n * 64 + bl;
        out[o +  0] = scalars[o +  0] + accS0;
        out[o + 16] = scalars[o + 16] + accS1;
        out[o + 32] = scalars[o + 32] + accS2;
        out[o + 48] = scalars[o + 48] + accS3;
        size_t ov = (size_t)n * 48 + 3 * bl;
        out[NS + ov + 0] = vectors[ov + 0] + accV0;
        out[NS + ov + 1] = vectors[ov + 1] + accV1;
        out[NS + ov + 2] = vectors[ov + 2] + accV2;
    }
}

extern "C" void kernel_launch(void* const* d_in, const int* in_sizes, int n_in,
                              void* d_out, int out_size, void* d_ws, size_t ws_size,
                              hipStream_t stream)
{
    const float* scalars  = (const float*)d_in[0];
    const float* vectors  = (const float*)d_in[1];
    const float* edge_vec = (const float*)d_in[2];
    const float* W1  = (const float*)d_in[3];
    const float* b1  = (const float*)d_in[4];
    const float* W2  = (const float*)d_in[5];
    const float* b2  = (const float*)d_in[6];
    const float* Wa1 = (const float*)d_in[7];
    const float* ba1 = (const float*)d_in[8];
    const float* Wa2 = (const float*)d_in[9];
    const float* ba2 = (const float*)d_in[10];
    const int* eidx  = (const int*)d_in[11];

    char* wsb = (char*)d_ws;
    // proven ~215.6 MB layout; P1/P2 f32 slots retained (now unused), f16 tables live
    // in the hbuf-region tail after tbl/tbl2 (region has 81.9 MB free past the h rows).
    float4* attsh = (float4*)wsb;                       // E float4
    float*  P1    = (float*)(wsb + (size_t)E_ * 16);    // NS floats (dead)
    float*  P2    = P1 + NS;                            // NS floats (dead)
    float*  hbuf  = P2 + NS;                            // region: 32E floats
    int* cnt       = (int*)(hbuf + (size_t)32 * E_);    // N
    int* bsum      = cnt + N_;                          // 40
    int* boff      = bsum + 64;                         // 40
    int* row_start = cnt + 2 * N_;                      // N+1
    int* perm      = row_start + N_ + 1;                // E
    int* srcbuf    = perm + E_;                         // E
    int*  rnk  = (int*)hbuf;                            // aliases hbuf region head (dead after k_place)
    uint* tbl  = (uint*)hbuf + (size_t)16 * E_;         // 1536
    uint* tbl2 = tbl + 1536;                            // 1536
    _Float16* P1h  = (_Float16*)(tbl2 + 1536);          // NS halves (5.12 MB)
    _Float16* P2h  = P1h + NS;                          // NS halves
    _Float16* sc16 = P2h + NS;                          // NS halves
    _Float16* vec16 = sc16 + NS;                        // NV halves (ends ~19.2 MB into the 81.9 MB tail)

    hipMemsetAsync(cnt, 0, (size_t)N_ * sizeof(int), stream);
    k_pack<<<12, 256, 0, stream>>>(W1, Wa1, W2, tbl, tbl2);
    k_rank<<<5000, 256, 0, stream>>>(eidx, cnt, rnk);
    k_scan1<<<40, 1024, 0, stream>>>(cnt, row_start, bsum);
    k_scan2<<<1, 64, 0, stream>>>(bsum, boff);
    k_scan3<<<40, 1024, 0, stream>>>(boff, row_start);
    k_place<<<5000, 256, 0, stream>>>(eidx, row_start, rnk, perm);
    k_precompute<<<10000, 256, 0, stream>>>(scalars, Wa1, ba1, P1h, P2h);
    k_convert<<<17500, 256, 0, stream>>>(scalars, vectors, sc16, vec16);
    k_edges_sorted<<<5000, 256, 0, stream>>>(edge_vec, eidx, perm, P1h, P2h,
                                             tbl, b1, Wa2, ba2,
                                             attsh, srcbuf, (uint*)hbuf);
    k_gather_mfma<<<10000, 256, 0, stream>>>(scalars, vectors, sc16, vec16, b2, row_start,
                                             attsh, srcbuf, (const uint*)hbuf, tbl2,
                                             (float*)d_out);
}

// Round 17
// 443.291 us; speedup vs baseline: 1.3091x; 1.0226x over previous
//
#include <hip/hip_runtime.h>

static constexpr int N_ = 40000;
static constexpr int E_ = 1280000;
static constexpr int NS = N_ * 64;      // 2,560,000 scalar elems
static constexpr int NV = N_ * 48;      // 1,920,000 vector elems

typedef _Float16 half2_t __attribute__((ext_vector_type(2)));
typedef _Float16 half8_t __attribute__((ext_vector_type(8)));
typedef float float4_t __attribute__((ext_vector_type(4)));
typedef unsigned int uint;

__device__ __forceinline__ float silu_f(float x) { return __fdividef(x, 1.f + __expf(-x)); }
__device__ __forceinline__ int rfl(int x) { return __builtin_amdgcn_readfirstlane(x); }

// ---- fused: per-node attention precompute (f16 rows) + f16 table conversion ----
__global__ void k_prep(const float* __restrict__ scalars, const float* __restrict__ vectors,
                       const float* __restrict__ Wa1, const float* __restrict__ ba1,
                       _Float16* __restrict__ P1h, _Float16* __restrict__ P2h,
                       _Float16* __restrict__ sc16, _Float16* __restrict__ vec16)
{
    int t = blockIdx.x * 256 + threadIdx.x;   // 17500*256 = NS+NV exactly
    if (t < NS) {
        int n = t >> 6, j = t & 63;
        float a1 = ba1[j];
        float a2 = 0.f;
        const float* srow = scalars + (size_t)n * 64;
#pragma unroll 8
        for (int k = 0; k < 64; k++) {
            float s = srow[k];
            a1 = fmaf(s, Wa1[k * 64 + j], a1);
            a2 = fmaf(s, Wa1[(64 + k) * 64 + j], a2);
        }
        P1h[t] = (_Float16)a1;
        P2h[t] = (_Float16)a2;
        sc16[t] = (_Float16)scalars[t];
    } else {
        vec16[t - NS] = (_Float16)vectors[t - NS];
    }
}

// ---- pack MFMA B tables (proven r13/r14): tbl = [Wa1_att|W1], tbl2 = W2 ----
__global__ void k_pack(const float* __restrict__ W1, const float* __restrict__ Wa1,
                       const float* __restrict__ W2, uint* __restrict__ tbl,
                       uint* __restrict__ tbl2)
{
    int t = blockIdx.x * 256 + threadIdx.x;
    if (t < 1536) {
        int j = t >> 4, q = t & 15;
        int k0 = 2 * q, k1 = 2 * q + 1;
        float a = (j < 64) ? Wa1[(128 + k0) * 64 + j] : W1[k0 * 32 + (j - 64)];
        float b = (j < 64) ? Wa1[(128 + k1) * 64 + j] : W1[k1 * 32 + (j - 64)];
        half2_t v; v.x = (_Float16)a; v.y = (_Float16)b;
        tbl[t] = __builtin_bit_cast(uint, v);
    } else if (t < 3072) {
        int tt = t - 1536;
        int j = tt >> 4, q = tt & 15;
        half2_t v;
        v.x = (_Float16)W2[(2 * q + 0) * 96 + j];
        v.y = (_Float16)W2[(2 * q + 1) * 96 + j];
        tbl2[tt] = __builtin_bit_cast(uint, v);
    }
}

// ================= CSR build (round-9 proven) =================
__global__ void k_rank(const int* __restrict__ eidx, int* __restrict__ cnt,
                       int* __restrict__ r)
{
    int e = blockIdx.x * 256 + threadIdx.x;
    r[e] = atomicAdd(&cnt[eidx[E_ + e]], 1);
}

__global__ void k_scan1(const int* __restrict__ cnt, int* __restrict__ row_start,
                        int* __restrict__ bsum)
{
    __shared__ int buf[1024];
    int b = blockIdx.x, tid = threadIdx.x;
    int idx = b * 1024 + tid;
    int v = (idx < N_) ? cnt[idx] : 0;
    buf[tid] = v;
    __syncthreads();
    for (int off = 1; off < 1024; off <<= 1) {
        int t = (tid >= off) ? buf[tid - off] : 0;
        __syncthreads();
        buf[tid] += t;
        __syncthreads();
    }
    if (idx < N_) row_start[idx] = buf[tid] - v;
    if (tid == 1023) bsum[b] = buf[1023];
}

__global__ void k_scan2(const int* __restrict__ bsum, int* __restrict__ boff)
{
    if (threadIdx.x == 0) {
        int s = 0;
        for (int b = 0; b < 40; b++) { boff[b] = s; s += bsum[b]; }
    }
}

__global__ void k_scan3(const int* __restrict__ boff, int* __restrict__ row_start)
{
    int idx = blockIdx.x * 1024 + threadIdx.x;
    if (idx < N_) row_start[idx] += boff[blockIdx.x];
    if (idx == N_) row_start[N_] = E_;
}

__global__ void k_place(const int* __restrict__ eidx, const int* __restrict__ row_start,
                        const int* __restrict__ r, int* __restrict__ perm)
{
    int e = blockIdx.x * 256 + threadIdx.x;
    int dst = eidx[E_ + e];
    perm[row_start[dst] + r[e]] = e;
}

// ================= edge phase: vs r16 — NO barriers (wave-private LDS), sin recurrence, ====
// ================= pk_add_f16 logit. Structure otherwise identical.                      ====
__global__ __launch_bounds__(256, 3) void k_edges_sorted(
    const float* __restrict__ edge_vec, const int* __restrict__ eidx,
    const int* __restrict__ perm,
    const _Float16* __restrict__ P1h, const _Float16* __restrict__ P2h,
    const uint* __restrict__ tbl, const float* __restrict__ b1,
    const float* __restrict__ Wa2, const float* __restrict__ ba2,
    float4* __restrict__ attsh, int* __restrict__ srcbuf, uint* __restrict__ hbufp)
{
    __shared__ char lds_raw[4 * 12544];
    int tid = threadIdx.x;
    int wid = tid >> 6, lane = tid & 63;
    char* wbase = lds_raw + wid * 12544;   // wave-private: no __syncthreads needed;
                                           // intra-wave ds ordering via compiler lgkmcnt
    int bl = lane & 15, bq = lane >> 4;

    int i = blockIdx.x * 256 + tid;
    int e = perm[i];
    int src = eidx[e];
    int dst = eidx[E_ + e];

    float ev0 = edge_vec[3 * e + 0];
    float ev1 = edge_vec[3 * e + 1];
    float ev2 = edge_vec[3 * e + 2];
    float d = sqrtf(fmaf(ev0, ev0, fmaf(ev1, ev1, ev2 * ev2)));
    float inv_d = __fdividef(1.f, fmaxf(d, 1e-8f));
    float cut = (d < 10.f) ? 0.5f * (__cosf(0.31415927f * d) + 1.f) : 0.f;
    float cutd = cut * inv_d;
    float sh0 = ev1 * inv_d, sh1 = ev2 * inv_d, sh2 = ev0 * inv_d;

    // rbf via sin recurrence: sin((k+1)t) = 2cos(t)sin(kt) - sin((k-1)t)
    float th = 0.31415927f * d;
    float scur = __sinf(th);
    float twoC = 2.f * __cosf(th);
    float sprev = 0.f;
    uint rbf2[16];
#pragma unroll
    for (int q = 0; q < 16; q++) {
        float r0 = scur * cutd;
        float snext = fmaf(twoC, scur, -sprev);
        sprev = scur; scur = snext;
        float r1 = scur * cutd;
        snext = fmaf(twoC, scur, -sprev);
        sprev = scur; scur = snext;
        half2_t v; v.x = (_Float16)r0; v.y = (_Float16)r1;
        rbf2[q] = __builtin_bit_cast(uint, v);
    }
    {
        uint4* rw = (uint4*)(wbase + lane * 64);
        rw[0] = make_uint4(rbf2[0], rbf2[1], rbf2[2], rbf2[3]);
        rw[1] = make_uint4(rbf2[4], rbf2[5], rbf2[6], rbf2[7]);
        rw[2] = make_uint4(rbf2[8], rbf2[9], rbf2[10], rbf2[11]);
        rw[3] = make_uint4(rbf2[12], rbf2[13], rbf2[14], rbf2[15]);
    }
    uint4 bfr[6];
#pragma unroll
    for (int u = 0; u < 6; u++)
        bfr[u] = *(const uint4*)(tbl + (u * 16 + bl) * 16 + bq * 4);

    uint4 afr[4];
#pragma unroll
    for (int t = 0; t < 4; t++)
        afr[t] = *(const uint4*)(wbase + (t * 16 + bl) * 64 + bq * 16);

    _Float16* gtile = (_Float16*)wbase;
#pragma unroll
    for (int t = 0; t < 4; t++) {
        half8_t av = __builtin_bit_cast(half8_t, afr[t]);
        int eb = t * 16 + bq * 4;
#pragma unroll
        for (int u = 0; u < 6; u++) {
            float4_t dd = __builtin_amdgcn_mfma_f32_16x16x32_f16(
                av, __builtin_bit_cast(half8_t, bfr[u]), (float4_t)(0.f), 0, 0, 0);
            int col = u * 16 + bl;
            gtile[(eb + 0) * 98 + col] = (_Float16)dd[0];
            gtile[(eb + 1) * 98 + col] = (_Float16)dd[1];
            gtile[(eb + 2) * 98 + col] = (_Float16)dd[2];
            gtile[(eb + 3) * 98 + col] = (_Float16)dd[3];
        }
    }
    const uint* grow = (const uint*)(wbase + (size_t)lane * 196);

    const uint2* p1h = (const uint2*)(P1h + (size_t)dst * 64);
    const uint2* p2h = (const uint2*)(P2h + (size_t)src * 64);
    float logit = ba2[0];
#pragma unroll
    for (int q = 0; q < 16; q++) {
        uint2 ua = p1h[q];
        uint2 ub = p2h[q];
        half2_t s01 = __builtin_bit_cast(half2_t, ua.x) + __builtin_bit_cast(half2_t, ub.x)
                    + __builtin_bit_cast(half2_t, grow[2 * q + 0]);
        half2_t s23 = __builtin_bit_cast(half2_t, ua.y) + __builtin_bit_cast(half2_t, ub.y)
                    + __builtin_bit_cast(half2_t, grow[2 * q + 1]);
        logit = fmaf(silu_f((float)s01.x), Wa2[4 * q + 0], logit);
        logit = fmaf(silu_f((float)s01.y), Wa2[4 * q + 1], logit);
        logit = fmaf(silu_f((float)s23.x), Wa2[4 * q + 2], logit);
        logit = fmaf(silu_f((float)s23.y), Wa2[4 * q + 3], logit);
    }
    float att = __fdividef(1.f, 1.f + __expf(-logit));

    uint hp[16];
#pragma unroll
    for (int q = 0; q < 16; q++) {
        half2_t gg = __builtin_bit_cast(half2_t, grow[32 + q]);
        half2_t v;
        v.x = (_Float16)silu_f((float)gg.x + b1[2 * q + 0]);
        v.y = (_Float16)silu_f((float)gg.y + b1[2 * q + 1]);
        hp[q] = __builtin_bit_cast(uint, v);
    }
    uint4* hrow4 = (uint4*)(hbufp + (size_t)i * 16);
#pragma unroll
    for (int q = 0; q < 4; q++)
        hrow4[q] = make_uint4(hp[4 * q + 0], hp[4 * q + 1], hp[4 * q + 2], hp[4 * q + 3]);
    attsh[i] = make_float4(att, sh0, sh1, sh2);
    srcbuf[i] = src;
}

// ================= gather (round-16 proven, unchanged) =================
__global__ __launch_bounds__(256, 4) void k_gather_mfma(
    const float* __restrict__ scalars, const float* __restrict__ vectors,
    const _Float16* __restrict__ sc16, const _Float16* __restrict__ vec16,
    const float* __restrict__ b2,
    const int* __restrict__ row_start,
    const float4* __restrict__ attsh, const int* __restrict__ srcbuf,
    const uint* __restrict__ hbuf, const uint* __restrict__ tbl2,
    float* __restrict__ out)
{
    int wid  = threadIdx.x >> 6;
    int lane = threadIdx.x & 63;
    int n    = blockIdx.x * 4 + wid;
    int bl = lane & 15, bq = lane >> 4;
    int rs = rfl(row_start[n]);
    int re = rfl(row_start[n + 1]);

    uint4 bfr2[6];
#pragma unroll
    for (int u = 0; u < 6; u++)
        bfr2[u] = *(const uint4*)(tbl2 + (u * 16 + bl) * 16 + bq * 4);

    float b2s[4];
#pragma unroll
    for (int u = 0; u < 4; u++) b2s[u] = b2[u * 16 + bl];
    float bvf = b2[64 + bl], bvg = b2[80 + bl];

    float accS0 = 0.f, accS1 = 0.f, accS2 = 0.f, accS3 = 0.f;
    float accV0 = 0.f, accV1 = 0.f, accV2 = 0.f;

    for (int i0 = rs; i0 < re; i0 += 16) {
        uint4 av4 = make_uint4(0u, 0u, 0u, 0u);
        if (i0 + bl < re)
            av4 = *(const uint4*)(hbuf + (size_t)(i0 + bl) * 16 + bq * 4);
        half8_t av = __builtin_bit_cast(half8_t, av4);

        float4_t d0 = __builtin_amdgcn_mfma_f32_16x16x32_f16(av, __builtin_bit_cast(half8_t, bfr2[0]), (float4_t)(0.f), 0, 0, 0);
        float4_t d1 = __builtin_amdgcn_mfma_f32_16x16x32_f16(av, __builtin_bit_cast(half8_t, bfr2[1]), (float4_t)(0.f), 0, 0, 0);
        float4_t d2 = __builtin_amdgcn_mfma_f32_16x16x32_f16(av, __builtin_bit_cast(half8_t, bfr2[2]), (float4_t)(0.f), 0, 0, 0);
        float4_t d3 = __builtin_amdgcn_mfma_f32_16x16x32_f16(av, __builtin_bit_cast(half8_t, bfr2[3]), (float4_t)(0.f), 0, 0, 0);
        float4_t d4 = __builtin_amdgcn_mfma_f32_16x16x32_f16(av, __builtin_bit_cast(half8_t, bfr2[4]), (float4_t)(0.f), 0, 0, 0);
        float4_t d5 = __builtin_amdgcn_mfma_f32_16x16x32_f16(av, __builtin_bit_cast(half8_t, bfr2[5]), (float4_t)(0.f), 0, 0, 0);

#pragma unroll
        for (int r = 0; r < 4; r++) {
            int slot = i0 + bq * 4 + r;
            int ok = (slot < re);
            int cs = ok ? slot : (re - 1);
            float4 as = attsh[cs];
            float att = ok ? as.x : 0.f;
            int src = srcbuf[cs];
            const _Float16* srow = sc16 + (size_t)src * 64 + bl;
            accS0 = fmaf(att * (float)srow[0],  d0[r] + b2s[0], accS0);
            accS1 = fmaf(att * (float)srow[16], d1[r] + b2s[1], accS1);
            accS2 = fmaf(att * (float)srow[32], d2[r] + b2s[2], accS2);
            accS3 = fmaf(att * (float)srow[48], d3[r] + b2s[3], accS3);
            float vf = d4[r] + bvf;
            float vg = d5[r] + bvg;
            const _Float16* vr = vec16 + (size_t)src * 48 + 3 * bl;
            accV0 = fmaf(att, fmaf((float)vr[0], vf, vg * as.y), accV0);
            accV1 = fmaf(att, fmaf((float)vr[1], vf, vg * as.z), accV1);
            accV2 = fmaf(att, fmaf((float)vr[2], vf, vg * as.w), accV2);
        }
    }

    accS0 += __shfl_xor(accS0, 16, 64); accS0 += __shfl_xor(accS0, 32, 64);
    accS1 += __shfl_xor(accS1, 16, 64); accS1 += __shfl_xor(accS1, 32, 64);
    accS2 += __shfl_xor(accS2, 16, 64); accS2 += __shfl_xor(accS2, 32, 64);
    accS3 += __shfl_xor(accS3, 16, 64); accS3 += __shfl_xor(accS3, 32, 64);
    accV0 += __shfl_xor(accV0, 16, 64); accV0 += __shfl_xor(accV0, 32, 64);
    accV1 += __shfl_xor(accV1, 16, 64); accV1 += __shfl_xor(accV1, 32, 64);
    accV2 += __shfl_xor(accV2, 16, 64); accV2 += __shfl_xor(accV2, 32, 64);

    if (bq == 0) {
        size_t o = (size_t)n * 64 + bl;
        out[o +  0] = scalars[o +  0] + accS0;
        out[o + 16] = scalars[o + 16] + accS1;
        out[o + 32] = scalars[o + 32] + accS2;
        out[o + 48] = scalars[o + 48] + accS3;
        size_t ov = (size_t)n * 48 + 3 * bl;
        out[NS + ov + 0] = vectors[ov + 0] + accV0;
        out[NS + ov + 1] = vectors[ov + 1] + accV1;
        out[NS + ov + 2] = vectors[ov + 2] + accV2;
    }
}

extern "C" void kernel_launch(void* const* d_in, const int* in_sizes, int n_in,
                              void* d_out, int out_size, void* d_ws, size_t ws_size,
                              hipStream_t stream)
{
    const float* scalars  = (const float*)d_in[0];
    const float* vectors  = (const float*)d_in[1];
    const float* edge_vec = (const float*)d_in[2];
    const float* W1  = (const float*)d_in[3];
    const float* b1  = (const float*)d_in[4];
    const float* W2  = (const float*)d_in[5];
    const float* b2  = (const float*)d_in[6];
    const float* Wa1 = (const float*)d_in[7];
    const float* ba1 = (const float*)d_in[8];
    const float* Wa2 = (const float*)d_in[9];
    const float* ba2 = (const float*)d_in[10];
    const int* eidx  = (const int*)d_in[11];

    char* wsb = (char*)d_ws;
    // proven ~215.6 MB layout (identical to round 16)
    float4* attsh = (float4*)wsb;                       // E float4
    float*  P1    = (float*)(wsb + (size_t)E_ * 16);    // NS floats (dead)
    float*  P2    = P1 + NS;                            // NS floats (dead)
    float*  hbuf  = P2 + NS;                            // region: 32E floats
    int* cnt       = (int*)(hbuf + (size_t)32 * E_);    // N
    int* bsum      = cnt + N_;                          // 40
    int* boff      = bsum + 64;                         // 40
    int* row_start = cnt + 2 * N_;                      // N+1
    int* perm      = row_start + N_ + 1;                // E
    int* srcbuf    = perm + E_;                         // E
    int*  rnk  = (int*)hbuf;                            // aliases hbuf region head (dead after k_place)
    uint* tbl  = (uint*)hbuf + (size_t)16 * E_;         // 1536
    uint* tbl2 = tbl + 1536;                            // 1536
    _Float16* P1h  = (_Float16*)(tbl2 + 1536);          // NS halves
    _Float16* P2h  = P1h + NS;                          // NS halves
    _Float16* sc16 = P2h + NS;                          // NS halves
    _Float16* vec16 = sc16 + NS;                        // NV halves

    hipMemsetAsync(cnt, 0, (size_t)N_ * sizeof(int), stream);
    k_pack<<<12, 256, 0, stream>>>(W1, Wa1, W2, tbl, tbl2);
    k_rank<<<5000, 256, 0, stream>>>(eidx, cnt, rnk);
    k_scan1<<<40, 1024, 0, stream>>>(cnt, row_start, bsum);
    k_scan2<<<1, 64, 0, stream>>>(bsum, boff);
    k_scan3<<<40, 1024, 0, stream>>>(boff, row_start);
    k_place<<<5000, 256, 0, stream>>>(eidx, row_start, rnk, perm);
    k_prep<<<17500, 256, 0, stream>>>(scalars, vectors, Wa1, ba1, P1h, P2h, sc16, vec16);
    k_edges_sorted<<<5000, 256, 0, stream>>>(edge_vec, eidx, perm, P1h, P2h,
                                             tbl, b1, Wa2, ba2,
                                             attsh, srcbuf, (uint*)hbuf);
    k_gather_mfma<<<10000, 256, 0, stream>>>(scalars, vectors, sc16, vec16, b2, row_start,
                                             attsh, srcbuf, (const uint*)hbuf, tbl2,
                                             (float*)d_out);
}